// Round 8
// baseline (906.813 us; speedup 1.0000x reference)
//
#include <hip/hip_runtime.h>
#include <stdint.h>

typedef unsigned short u16;
typedef __bf16 bf16t;
typedef bf16t bf16x8 __attribute__((ext_vector_type(8)));
typedef float f32x4 __attribute__((ext_vector_type(4)));
typedef unsigned long long ull;

#define NROWS 100000
#define DD 512
#define QD 128
#define KSEL 20000
#define NB2 782   // ceil(100000/128)

// ---------- helpers ----------
__device__ __forceinline__ uint32_t fmono(float x){
  uint32_t u = __float_as_uint(x);
  return (u & 0x80000000u) ? ~u : (u | 0x80000000u);
}
__device__ __forceinline__ u16 f2bf(float x){  // RNE float->bf16 bits
  uint32_t u = __float_as_uint(x);
  u += 0x7fffu + ((u >> 16) & 1u);
  return (u16)(u >> 16);
}
__device__ __forceinline__ uint32_t pkbf(float a, float b){
  return (uint32_t)f2bf(a) | ((uint32_t)f2bf(b) << 16);
}

struct Scal {
  uint32_t sel_hi, cnt_before, keyT, gmk;
  float Z;
  uint32_t pad0, pad1, pad2;
  ull ck[2];   // argmax keys for c columns
};

#define MFMA16(A,B,C) __builtin_amdgcn_mfma_f32_16x16x32_bf16(A,B,C,0,0,0)

// ---------- k_conv: weights -> bf16, hist1 accumulate, sc init ----------
__global__ void k_conv(const float* __restrict__ Wl, const float* __restrict__ Wv,
                       const float* __restrict__ Wq, const float* __restrict__ preds,
                       u16* __restrict__ wl_bf, u16* __restrict__ wvq_bf,
                       uint32_t* __restrict__ hist1, Scal* sc){
  int idx = blockIdx.x*256 + threadIdx.x;          // 589824 total
  if (idx < 262144) wl_bf[idx] = f2bf(Wl[idx]);
  int e = idx - 262144;
  if (e >= 0) wvq_bf[e] = f2bf(e < 262144 ? Wv[e] : Wq[e - 262144]);
  if (idx < NROWS) atomicAdd(&hist1[fmono(preds[idx]) >> 16], 1u);
  if (idx == 0){ sc->Z = 0.f; sc->ck[0] = 0ull; sc->ck[1] = 0ull; sc->gmk = 0u; }
}

// ---------- k_sel1 / k_hist2 / k_sel2 (round-5 proven) ----------
__global__ void k_sel1(const uint32_t* __restrict__ hist, Scal* sc){
  __shared__ uint32_t part[256], binv[256];
  __shared__ uint32_t sp, sbase;
  int t = threadIdx.x;
  uint32_t s = 0;
  const uint4* h4 = (const uint4*)(hist + t*256);
  #pragma unroll 8
  for (int i = 0; i < 64; ++i){ uint4 v = h4[i]; s += v.x + v.y + v.z + v.w; }
  part[t] = s; __syncthreads();
  if (t == 0){
    uint32_t cum = 0;
    for (int p = 0; p < 256; ++p){
      if (cum + part[p] >= KSEL){ sp = (uint32_t)p; sbase = cum; break; }
      cum += part[p];
    }
  }
  __syncthreads();
  binv[t] = hist[sp*256 + t];
  __syncthreads();
  if (t == 0){
    uint32_t c2 = sbase, p = sp;
    for (int b = 0; b < 256; ++b){
      uint32_t hb = binv[b];
      if (c2 + hb >= KSEL){ sc->sel_hi = p*256 + (uint32_t)b; sc->cnt_before = c2; break; }
      c2 += hb;
    }
  }
}

__global__ void k_hist2(const float* __restrict__ preds, const Scal* sc, uint32_t* __restrict__ hist){
  int idx = blockIdx.x*256 + threadIdx.x;
  uint32_t sh = sc->sel_hi;
  if (idx < NROWS){
    uint32_t key = fmono(preds[idx]);
    if ((key >> 16) == sh) atomicAdd(&hist[key & 0xffffu], 1u);
  }
}

__global__ void k_sel2(const uint32_t* __restrict__ hist, Scal* sc){
  __shared__ uint32_t part[256], binv[256];
  __shared__ uint32_t sp, sbase;
  int t = threadIdx.x;
  uint32_t target = KSEL - sc->cnt_before;
  uint32_t s = 0;
  const uint4* h4 = (const uint4*)(hist + t*256);
  #pragma unroll 8
  for (int i = 0; i < 64; ++i){ uint4 v = h4[i]; s += v.x + v.y + v.z + v.w; }
  part[t] = s; __syncthreads();
  if (t == 0){
    uint32_t cum = 0;
    for (int p = 0; p < 256; ++p){
      if (cum + part[p] >= target){ sp = (uint32_t)p; sbase = cum; break; }
      cum += part[p];
    }
  }
  __syncthreads();
  binv[t] = hist[sp*256 + t];
  __syncthreads();
  if (t == 0){
    uint32_t c2 = sbase, p = sp;
    for (int b = 0; b < 256; ++b){
      uint32_t hb = binv[b];
      if (c2 + hb >= target){ sc->keyT = (sc->sel_hi << 16) | (p*256 + (uint32_t)b); break; }
      c2 += hb;
    }
  }
}

// ---------- k_zc: Z = sum exp(pm) and argmax keys of c cols (multi-block) ----------
__global__ void k_zc(const float* __restrict__ preds, const float* __restrict__ c, Scal* sc){
  int idx = blockIdx.x*256 + threadIdx.x;
  uint32_t kT = sc->keyT;
  float s = 0.f;
  ull k0 = 0, k1 = 0;
  if (idx < NROWS){
    float p = preds[idx];
    float pm = (fmono(p) <= kT) ? 0.0f : p;
    s = __expf(pm);
    uint32_t inv = ~(uint32_t)idx;
    k0 = ((ull)fmono(c[(size_t)idx*2 + 0]) << 32) | inv;
    k1 = ((ull)fmono(c[(size_t)idx*2 + 1]) << 32) | inv;
  }
  #pragma unroll
  for (int off = 32; off; off >>= 1){
    s += __shfl_xor(s, off);
    ull o0 = __shfl_xor(k0, off); if (o0 > k0) k0 = o0;
    ull o1 = __shfl_xor(k1, off); if (o1 > k1) k1 = o1;
  }
  if ((threadIdx.x & 63) == 0){
    atomicAdd(&sc->Z, s);
    atomicMax(&sc->ck[0], k0); atomicMax(&sc->ck[1], k1);
  }
}

// ---------- k_mq: m_feats (exact fp32) + q_max (round-5 proven) ----------
__launch_bounds__(1024)
__global__ void k_mq(const float* __restrict__ feats, const float* __restrict__ preds,
                     const float* __restrict__ Wl, const float* __restrict__ bl,
                     const float* __restrict__ Wq, const float* __restrict__ bq,
                     const Scal* __restrict__ sc, float* __restrict__ qmv){
  __shared__ float fmL[2][512];
  int t = threadIdx.x;
  int j = t >> 9, n = t & 511;
  uint32_t m = ~(uint32_t)(sc->ck[j] & 0xffffffffull);
  float p = preds[m];
  float pm = (fmono(p) <= sc->keyT) ? 0.f : p;
  float g = 1.f + __expf(pm) / sc->Z;
  const float4* fr4 = (const float4*)(feats + (size_t)m * DD);
  const float4* wr4 = (const float4*)(Wl + (size_t)n * DD);
  float acc[4] = {0.f, 0.f, 0.f, 0.f};
  #pragma unroll 4
  for (int k = 0; k < 128; ++k){
    float4 x = fr4[k], w = wr4[k];
    acc[k & 3] += x.x*w.x + x.y*w.y + x.z*w.z + x.w*w.w;
  }
  float v = bl[n] + g * ((acc[0] + acc[1]) + (acc[2] + acc[3]));
  fmL[j][n] = v > 0.f ? v : 0.f;
  __syncthreads();
  if (t < 256){
    int jj = t >> 7, q = t & 127;
    const float4* f4 = (const float4*)fmL[jj];
    const float4* w4 = (const float4*)(Wq + (size_t)q * DD);
    float a2[4] = {0.f, 0.f, 0.f, 0.f};
    #pragma unroll 4
    for (int k = 0; k < 128; ++k){
      float4 x = f4[k], w = w4[k];
      a2[k & 3] += x.x*w.x + x.y*w.y + x.z*w.z + x.w*w.w;
    }
    qmv[jj*QD + q] = tanhf(bq[q] + (a2[0] + a2[1]) + (a2[2] + a2[3]));
  }
}

// ---------- k_f: f = relu(gX @ Wl^T + bl), M=128/block, all 512 cols ----------
// LDS u16[20480]: Adb [2][128][40] @0 ; Bdb [2][128][40] @10240.
// F-transpose overlay [128][144] u16 (18432) @0 after each n-chunk.
// f_ws layout: [block][nt 0..3][row 0..127][col 0..127] bf16.
__launch_bounds__(256, 3)
__global__ void k_f(const float* __restrict__ feats, const float* __restrict__ preds,
                    const u16* __restrict__ wl, const float* __restrict__ bl,
                    const Scal* __restrict__ sc, u16* __restrict__ fout){
  __shared__ __align__(16) u16 lds[20480];
  const int tid = threadIdx.x;
  const int lane = tid & 63, quad = lane >> 4, l16 = lane & 15;
  const int wave = tid >> 6, wm = wave >> 1, wn = wave & 1;
  const long i0 = (long)blockIdx.x * 128;
  const int row = tid >> 1, kseg = tid & 1;
  long ir = i0 + row; if (ir >= NROWS) ir = NROWS - 1;
  float g;
  {
    float p = preds[ir];
    float pm = (fmono(p) <= sc->keyT) ? 0.f : p;
    g = 1.f + __expf(pm) / sc->Z;
  }
  const float* abase = feats + ir*DD + kseg*16;
  const u16* bbase0 = wl + (size_t)row*DD + kseg*16;
  u16* aw = lds + row*40 + kseg*16;
  u16* bw = lds + 10240 + row*40 + kseg*16;

  for (int nt = 0; nt < 4; ++nt){
    const u16* bbase = bbase0 + (size_t)nt*128*DD;
    f32x4 acc[4][4];
    #pragma unroll
    for (int mi = 0; mi < 4; ++mi)
      #pragma unroll
      for (int ni = 0; ni < 4; ++ni) acc[mi][ni] = (f32x4){0.f,0.f,0.f,0.f};

    float4 ar0, ar1, ar2, ar3;
    uint4 br0, br1;
    // prologue: chunk 0
    ar0 = *(const float4*)(abase + 0); ar1 = *(const float4*)(abase + 4);
    ar2 = *(const float4*)(abase + 8); ar3 = *(const float4*)(abase + 12);
    br0 = *(const uint4*)(bbase + 0);  br1 = *(const uint4*)(bbase + 8);
    __syncthreads();   // previous n-chunk LDS reads done
    {
      uint4 pk0, pk1;
      pk0.x = pkbf(ar0.x*g, ar0.y*g); pk0.y = pkbf(ar0.z*g, ar0.w*g);
      pk0.z = pkbf(ar1.x*g, ar1.y*g); pk0.w = pkbf(ar1.z*g, ar1.w*g);
      pk1.x = pkbf(ar2.x*g, ar2.y*g); pk1.y = pkbf(ar2.z*g, ar2.w*g);
      pk1.z = pkbf(ar3.x*g, ar3.y*g); pk1.w = pkbf(ar3.z*g, ar3.w*g);
      *(uint4*)(aw) = pk0; *(uint4*)(aw + 8) = pk1;
      *(uint4*)(bw) = br0; *(uint4*)(bw + 8) = br1;
    }
    // chunk 1 into regs
    ar0 = *(const float4*)(abase + 32); ar1 = *(const float4*)(abase + 36);
    ar2 = *(const float4*)(abase + 40); ar3 = *(const float4*)(abase + 44);
    br0 = *(const uint4*)(bbase + 32);  br1 = *(const uint4*)(bbase + 40);
    __syncthreads();   // buf0 visible

    for (int ks = 0; ks < 16; ++ks){
      const int cur = ks & 1;
      if (ks < 15){
        uint4 pk0, pk1;
        pk0.x = pkbf(ar0.x*g, ar0.y*g); pk0.y = pkbf(ar0.z*g, ar0.w*g);
        pk0.z = pkbf(ar1.x*g, ar1.y*g); pk0.w = pkbf(ar1.z*g, ar1.w*g);
        pk1.x = pkbf(ar2.x*g, ar2.y*g); pk1.y = pkbf(ar2.z*g, ar2.w*g);
        pk1.z = pkbf(ar3.x*g, ar3.y*g); pk1.w = pkbf(ar3.z*g, ar3.w*g);
        int nxt = cur ^ 1;
        *(uint4*)(aw + nxt*5120) = pk0; *(uint4*)(aw + nxt*5120 + 8) = pk1;
        *(uint4*)(bw + nxt*5120) = br0; *(uint4*)(bw + nxt*5120 + 8) = br1;
      }
      if (ks < 14){
        ar0 = *(const float4*)(abase + (ks+2)*32);      ar1 = *(const float4*)(abase + (ks+2)*32 + 4);
        ar2 = *(const float4*)(abase + (ks+2)*32 + 8);  ar3 = *(const float4*)(abase + (ks+2)*32 + 12);
        br0 = *(const uint4*)(bbase + (ks+2)*32);       br1 = *(const uint4*)(bbase + (ks+2)*32 + 8);
      }
      const u16* A = lds + cur*5120;
      const u16* B = lds + 10240 + cur*5120;
      bf16x8 af[4], bfm[4];
      #pragma unroll
      for (int mi = 0; mi < 4; ++mi) af[mi] = *(const bf16x8*)&A[(wm*64 + mi*16 + l16)*40 + quad*8];
      #pragma unroll
      for (int ni = 0; ni < 4; ++ni) bfm[ni] = *(const bf16x8*)&B[(wn*64 + ni*16 + l16)*40 + quad*8];
      #pragma unroll
      for (int mi = 0; mi < 4; ++mi)
        #pragma unroll
        for (int ni = 0; ni < 4; ++ni)
          acc[mi][ni] = MFMA16(af[mi], bfm[ni], acc[mi][ni]);
      __syncthreads();
    }

    // epilogue: bias + relu -> F overlay (stride 144) -> coalesced store
    float blv[4];
    #pragma unroll
    for (int ni = 0; ni < 4; ++ni) blv[ni] = bl[nt*128 + wn*64 + ni*16 + l16];
    #pragma unroll
    for (int mi = 0; mi < 4; ++mi)
      #pragma unroll
      for (int ni = 0; ni < 4; ++ni){
        int col = wn*64 + ni*16 + l16;
        int rb = wm*64 + mi*16 + quad*4;
        #pragma unroll
        for (int e = 0; e < 4; ++e){
          float v = acc[mi][ni][e] + blv[ni];
          lds[(rb + e)*144 + col] = f2bf(v > 0.f ? v : 0.f);
        }
      }
    __syncthreads();
    #pragma unroll
    for (int i = 0; i < 8; ++i){
      int ch = i*256 + tid;
      int r = ch >> 4, seg = ch & 15;
      *(uint4*)(fout + (((size_t)blockIdx.x*4 + nt)*128 + r)*128 + seg*8) =
          *(const uint4*)&lds[r*144 + seg*8];
    }
  }
}

// ---------- k_vq: [Q|V] = f @ W^T, M=128/block; Q first -> e, then e-weighted V ----------
__launch_bounds__(256, 3)
__global__ void k_vq(const u16* __restrict__ f, const u16* __restrict__ wvq,
                     const float* __restrict__ bv, const float* __restrict__ bq,
                     const float* __restrict__ qmv,
                     float* __restrict__ gpart, float* __restrict__ gpartE,
                     float* __restrict__ Aout){
  __shared__ __align__(16) u16 lds[20480];
  __shared__ __align__(16) float Ef[256];
  float* sred = (float*)(lds + 10240);   // overlay on Bdb: [128][2 j][2 wn]
  const int tid = threadIdx.x;
  const int lane = tid & 63, quad = lane >> 4, l16 = lane & 15;
  const int wave = tid >> 6, wm = wave >> 1, wn = wave & 1;
  const long i0 = (long)blockIdx.x * 128;
  const int row = tid >> 1, kseg = tid & 1;
  const u16* abase0 = f + ((size_t)blockIdx.x*4*128)*128 + (size_t)row*128 + kseg*16;
  u16* aw = lds + row*40 + kseg*16;
  u16* bw = lds + 10240 + row*40 + kseg*16;

  for (int nt2 = 0; nt2 < 5; ++nt2){
    const int colbase = (nt2 == 0) ? 512 : (nt2 - 1)*128;
    const u16* bbase = wvq + (size_t)(colbase + row)*DD + kseg*16;
    f32x4 acc[4][4];
    #pragma unroll
    for (int mi = 0; mi < 4; ++mi)
      #pragma unroll
      for (int ni = 0; ni < 4; ++ni) acc[mi][ni] = (f32x4){0.f,0.f,0.f,0.f};

    uint4 a0, a1, b0, b1;
    // A chunk ks: at abase0 + (ks>>2)*128*128 + (ks&3)*32
    a0 = *(const uint4*)(abase0 + 0); a1 = *(const uint4*)(abase0 + 8);
    b0 = *(const uint4*)(bbase + 0);  b1 = *(const uint4*)(bbase + 8);
    __syncthreads();
    *(uint4*)(aw) = a0; *(uint4*)(aw + 8) = a1;
    *(uint4*)(bw) = b0; *(uint4*)(bw + 8) = b1;
    a0 = *(const uint4*)(abase0 + 32); a1 = *(const uint4*)(abase0 + 40);
    b0 = *(const uint4*)(bbase + 32);  b1 = *(const uint4*)(bbase + 40);
    __syncthreads();

    for (int ks = 0; ks < 16; ++ks){
      const int cur = ks & 1;
      if (ks < 15){
        int nxt = cur ^ 1;
        *(uint4*)(aw + nxt*5120) = a0; *(uint4*)(aw + nxt*5120 + 8) = a1;
        *(uint4*)(bw + nxt*5120) = b0; *(uint4*)(bw + nxt*5120 + 8) = b1;
      }
      if (ks < 14){
        int kn = ks + 2;
        const u16* ap = abase0 + (size_t)(kn >> 2)*16384 + (kn & 3)*32;
        a0 = *(const uint4*)(ap);                b1 = *(const uint4*)(bbase + kn*32 + 8);
        a1 = *(const uint4*)(ap + 8);            b0 = *(const uint4*)(bbase + kn*32);
      }
      const u16* A = lds + cur*5120;
      const u16* B = lds + 10240 + cur*5120;
      bf16x8 af[4], bfm[4];
      #pragma unroll
      for (int mi = 0; mi < 4; ++mi) af[mi] = *(const bf16x8*)&A[(wm*64 + mi*16 + l16)*40 + quad*8];
      #pragma unroll
      for (int ni = 0; ni < 4; ++ni) bfm[ni] = *(const bf16x8*)&B[(wn*64 + ni*16 + l16)*40 + quad*8];
      #pragma unroll
      for (int mi = 0; mi < 4; ++mi)
        #pragma unroll
        for (int ni = 0; ni < 4; ++ni)
          acc[mi][ni] = MFMA16(af[mi], bfm[ni], acc[mi][ni]);
      __syncthreads();
    }

    if (nt2 == 0){
      // ---- Q epilogue ----
      float p0[4][4], p1[4][4];
      #pragma unroll
      for (int mi = 0; mi < 4; ++mi)
        #pragma unroll
        for (int e = 0; e < 4; ++e){ p0[mi][e] = 0.f; p1[mi][e] = 0.f; }
      #pragma unroll
      for (int ni = 0; ni < 4; ++ni){
        int qc = wn*64 + ni*16 + l16;
        float bqv = bq[qc], q0 = qmv[qc], q1 = qmv[QD + qc];
        #pragma unroll
        for (int mi = 0; mi < 4; ++mi)
          #pragma unroll
          for (int e = 0; e < 4; ++e){
            float tq = tanhf(acc[mi][ni][e] + bqv);
            p0[mi][e] += tq * q0;
            p1[mi][e] += tq * q1;
          }
      }
      #pragma unroll
      for (int off = 1; off <= 8; off <<= 1)
        #pragma unroll
        for (int mi = 0; mi < 4; ++mi)
          #pragma unroll
          for (int e = 0; e < 4; ++e){
            p0[mi][e] += __shfl_xor(p0[mi][e], off);
            p1[mi][e] += __shfl_xor(p1[mi][e], off);
          }
      if (l16 == 0){
        #pragma unroll
        for (int mi = 0; mi < 4; ++mi)
          #pragma unroll
          for (int e = 0; e < 4; ++e){
            int r = wm*64 + mi*16 + quad*4 + e;
            sred[(r*2 + 0)*2 + wn] = p0[mi][e];
            sred[(r*2 + 1)*2 + wn] = p1[mi][e];
          }
      }
      __syncthreads();
      {
        int r = tid >> 1, j = tid & 1;
        float sv = (sred[(r*2 + j)*2 + 0] + sred[(r*2 + j)*2 + 1]) * 0.08838834764831845f;
        bool valid = (i0 + r) < NROWS;
        float ev = valid ? __expf(sv) : 0.f;
        Ef[r*2 + j] = ev;
        if (valid) Aout[(i0 + r)*2 + j] = ev;
        float t2 = ev;
        #pragma unroll
        for (int off = 2; off <= 32; off <<= 1) t2 += __shfl_xor(t2, off);
        if (lane < 2) gpartE[(size_t)blockIdx.x*8 + wave*2 + j] = t2;
      }
      __syncthreads();   // Ef visible; sred reads done before next staging
    } else {
      // ---- V epilogue: e-weighted column sums ----
      float e0[4][4], e1[4][4];
      #pragma unroll
      for (int mi = 0; mi < 4; ++mi)
        #pragma unroll
        for (int e = 0; e < 4; ++e){
          int r = wm*64 + mi*16 + quad*4 + e;
          e0[mi][e] = Ef[r*2 + 0];
          e1[mi][e] = Ef[r*2 + 1];
        }
      #pragma unroll
      for (int ni = 0; ni < 4; ++ni){
        int colv = (nt2 - 1)*128 + wn*64 + ni*16 + l16;
        float bvv = bv[colv];
        float s0 = 0.f, s1 = 0.f;
        #pragma unroll
        for (int mi = 0; mi < 4; ++mi)
          #pragma unroll
          for (int e = 0; e < 4; ++e){
            float v = acc[mi][ni][e] + bvv;
            s0 += v * e0[mi][e];
            s1 += v * e1[mi][e];
          }
        s0 += __shfl_xor(s0, 16); s0 += __shfl_xor(s0, 32);
        s1 += __shfl_xor(s1, 16); s1 += __shfl_xor(s1, 32);
        if (quad == 0){
          gpart[((size_t)blockIdx.x*2 + wm)*1024 + colv]       = s0;
          gpart[((size_t)blockIdx.x*2 + wm)*1024 + 512 + colv] = s1;
        }
      }
    }
  }
}

// ---------- k_red: reduce partials -> sumEV[1024], sumE[2] ----------
__global__ void k_red(const float* __restrict__ gpart, const float* __restrict__ gpartE,
                      float* __restrict__ sumEV, float* __restrict__ sumE){
  const int t = threadIdx.x;
  if (blockIdx.x == 256){
    __shared__ float r0[256], r1[256];
    float s0 = 0.f, s1 = 0.f;
    for (int i = t; i < NB2*4; i += 256){ s0 += gpartE[(size_t)i*2]; s1 += gpartE[(size_t)i*2 + 1]; }
    r0[t] = s0; r1[t] = s1;
    __syncthreads();
    for (int st = 128; st; st >>= 1){
      if (t < st){ r0[t] += r0[t + st]; r1[t] += r1[t + st]; }
      __syncthreads();
    }
    if (t == 0){ sumE[0] = r0[0]; sumE[1] = r1[0]; }
    return;
  }
  __shared__ float4 red[256];
  int col4 = blockIdx.x * 4;
  float4 s = {0.f, 0.f, 0.f, 0.f};
  for (int r = t; r < NB2*2; r += 256){
    float4 v = *(const float4*)(gpart + (size_t)r*1024 + col4);
    s.x += v.x; s.y += v.y; s.z += v.z; s.w += v.w;
  }
  red[t] = s;
  __syncthreads();
  for (int st = 128; st; st >>= 1){
    if (t < st){
      float4 o = red[t + st];
      red[t].x += o.x; red[t].y += o.y; red[t].z += o.z; red[t].w += o.w;
    }
    __syncthreads();
  }
  if (t == 0) *(float4*)(sumEV + col4) = red[0];
}

// ---------- k_post: normalize A; compute B and Cout ----------
__global__ void k_post(float* __restrict__ out, const float* __restrict__ sumE,
                       const float* __restrict__ sumEV, const float* __restrict__ Wfcc,
                       const float* __restrict__ bfcc){
  if (blockIdx.x < 782){
    int idx = blockIdx.x*256 + threadIdx.x;
    if (idx < 200000) out[2 + idx] = out[2 + idx] / sumE[idx & 1];
    return;
  }
  __shared__ float red[512];
  int t = threadIdx.x;
  float z0 = sumE[0], z1 = sumE[1];
  float c0 = 0.f, c1 = 0.f;
  for (int e = t; e < 1024; e += 256){
    float bvv = sumEV[e] / ((e >> 9) ? z1 : z0);
    out[200002 + e] = bvv;
    c0 += bvv * Wfcc[e];
    c1 += bvv * Wfcc[1024 + e];
  }
  red[t] = c0; red[256 + t] = c1;
  __syncthreads();
  for (int s = 128; s; s >>= 1){
    if (t < s){ red[t] += red[t + s]; red[256 + t] += red[256 + t + s]; }
    __syncthreads();
  }
  if (t == 0){ out[0] = red[0] + bfcc[0]; out[1] = red[256] + bfcc[1]; }
}

// ---------- launch ----------
extern "C" void kernel_launch(void* const* d_in, const int* in_sizes, int n_in,
                              void* d_out, int out_size, void* d_ws, size_t ws_size,
                              hipStream_t stream){
  (void)in_sizes; (void)n_in; (void)out_size; (void)ws_size;
  const float* feats = (const float*)d_in[0];
  const float* c     = (const float*)d_in[1];
  const float* preds = (const float*)d_in[2];
  const float* W_lin = (const float*)d_in[3];
  const float* b_lin = (const float*)d_in[4];
  const float* W_q   = (const float*)d_in[5];
  const float* b_q   = (const float*)d_in[6];
  const float* W_v   = (const float*)d_in[7];
  const float* b_v   = (const float*)d_in[8];
  const float* W_fcc = (const float*)d_in[9];
  const float* b_fcc = (const float*)d_in[10];
  float* out = (float*)d_out;
  char* ws = (char*)d_ws;

  // ws layout (bytes)
  uint32_t* hist1  = (uint32_t*)(ws + 0);        // 262144
  uint32_t* hist2  = (uint32_t*)(ws + 262144);   // 262144 -> 524288
  Scal*     sc     = (Scal*)(ws + 524288);       // 64     -> 524352
  float*    qmv    = (float*)(ws + 524352);      // 1024   -> 525376
  float*    sumE   = (float*)(ws + 525376);      // 64     -> 525440
  float*    sumEV  = (float*)(ws + 525440);      // 4096   -> 529536
  float*    gpartE = (float*)(ws + 529536);      // 782*8*4 = 25024 (pad 25088) -> 554624
  u16*      wl_bf  = (u16*)(ws + 554624);        // 524288 -> 1078912
  u16*      wvq_bf = (u16*)(ws + 1078912);       // 655360 -> 1734272
  float*    gpart  = (float*)(ws + 1734272);     // 1564*1024*4 = 6406144 -> 8140416
  u16*      f_ws   = (u16*)(ws + 8140416);       // 782*4*128*128*2 = 102498304 -> 110638720

  hipMemsetAsync(ws, 0, 524288, stream);   // hist1 + hist2

  k_conv <<<2304, 256, 0, stream>>>(W_lin, W_v, W_q, preds, wl_bf, wvq_bf, hist1, sc);
  k_sel1 <<<1, 256, 0, stream>>>(hist1, sc);
  k_hist2<<<391, 256, 0, stream>>>(preds, sc, hist2);
  k_sel2 <<<1, 256, 0, stream>>>(hist2, sc);
  k_zc   <<<391, 256, 0, stream>>>(preds, c, sc);
  k_mq   <<<1, 1024, 0, stream>>>(feats, preds, W_lin, b_lin, W_q, b_q, sc, qmv);
  k_f    <<<NB2, 256, 0, stream>>>(feats, preds, wl_bf, b_lin, sc, f_ws);
  k_vq   <<<NB2, 256, 0, stream>>>(f_ws, wvq_bf, b_v, b_q, qmv, gpart, gpartE, out + 2);
  k_red  <<<257, 256, 0, stream>>>(gpart, gpartE, sumEV, sumE);
  k_post <<<783, 256, 0, stream>>>(out, sumE, sumEV, W_fcc, b_fcc);
}